// Round 4
// baseline (210.884 us; speedup 1.0000x reference)
//
#include <hip/hip_runtime.h>

typedef __bf16 bf16_8 __attribute__((ext_vector_type(8)));
typedef __bf16 bf16_4 __attribute__((ext_vector_type(4)));
typedef float  f32x4  __attribute__((ext_vector_type(4)));

#define NB 32
#define NT 2048
#define NC 384
#define NH 64

static __device__ __forceinline__ f32x4 mfma16(bf16_8 a, bf16_8 b, f32x4 c) {
  return __builtin_amdgcn_mfma_f32_16x16x32_bf16(a, b, c, 0, 0, 0);
}

// ---- kernel 1: pack weights: fp32 [C,H] x3 -> bf16 Wt[n][k], n: 0-63=Q(Wq*0.125*log2e), 64-127=K, 128-191=V
__global__ void pack_w_kernel(const float* __restrict__ Wk, const float* __restrict__ Wq,
                              const float* __restrict__ Wv, __bf16* __restrict__ Wt) {
  int idx = blockIdx.x * 256 + threadIdx.x;
  if (idx >= 192 * NC) return;
  int n = idx / NC, k = idx % NC;
  int sel = n >> 6, h = n & 63;
  const float* W = (sel == 0) ? Wq : (sel == 1 ? Wk : Wv);
  float v = W[k * NH + h];
  // fold attention scale H^-0.5 = 0.125 AND log2(e) so softmax runs on native exp2
  if (sel == 0) v *= 0.125f * 1.44269504088896340736f;
  Wt[idx] = (__bf16)v;
}

// ---- kernel 2: QKV projection with the ENTIRE Wt in LDS (147,456 B, XOR-swizzled).
// Block = 1024 threads (16 waves), 256 rows/block, grid 256 = 1 block/CU.
// This round: Q/K epilogue routed through LDS (reusing the W region) so ALL
// global stores are coalesced 16B (was: 32 scalar 2B stores/thread in 32B segments).
__launch_bounds__(1024, 4)
__global__ void qkv_kernel(const float* __restrict__ x, const __bf16* __restrict__ Wt,
                           __bf16* __restrict__ Q, __bf16* __restrict__ K,
                           __bf16* __restrict__ Vt) {
  __shared__ __bf16 Wl[192 * 384];  // 147,456 B; chunk c of row r stored at c^(r&7)

  const int tid  = threadIdx.x;
  const int lane = tid & 63, wq = tid >> 6;
  const int quad = lane >> 4, l16 = lane & 15;
  const int rowblk = blockIdx.x * 256;
  const int rbase  = rowblk + wq * 16;
  const int row    = rbase + l16;  // this lane's x row

  // stage Wt -> LDS, 16-B chunks, XOR swizzle. 9216 chunks / 1024 threads = 9 each.
  #pragma unroll
  for (int i = 0; i < 9; ++i) {
    int g = tid + i * 1024;
    int r = g / 48, c = g - r * 48;
    int p = c ^ (r & 7);
    uint4 v = ((const uint4*)Wt)[g];
    *(uint4*)&Wl[(r * 48 + p) * 8] = v;
  }
  __syncthreads();

  f32x4 acc[12];
  #pragma unroll
  for (int n = 0; n < 12; ++n) acc[n] = f32x4{0.f, 0.f, 0.f, 0.f};

  const float* xrow = x + (size_t)row * NC;
  f32x4 x0 = *(const f32x4*)(xrow + quad * 8);
  f32x4 x1 = *(const f32x4*)(xrow + quad * 8 + 4);

  #pragma unroll
  for (int kc = 0; kc < 12; ++kc) {
    f32x4 nx0, nx1;
    if (kc < 11) {  // prefetch next x slab before the MFMA chain
      const float* xp = xrow + (kc + 1) * 32 + quad * 8;
      nx0 = *(const f32x4*)xp;
      nx1 = *(const f32x4*)(xp + 4);
    }
    bf16_8 a;
    a[0] = (__bf16)x0[0]; a[1] = (__bf16)x0[1]; a[2] = (__bf16)x0[2]; a[3] = (__bf16)x0[3];
    a[4] = (__bf16)x1[0]; a[5] = (__bf16)x1[1]; a[6] = (__bf16)x1[2]; a[7] = (__bf16)x1[3];
    const int pc = (kc * 4 + quad) ^ (l16 & 7);  // swizzled chunk within row
    const int cbase = l16 * 48 + pc;             // row l16 (+ n*16 rows below)
    #pragma unroll
    for (int n = 0; n < 12; ++n) {
      bf16_8 b = *(const bf16_8*)&Wl[(n * 16 * 48 + cbase) * 8];
      acc[n] = mfma16(a, b, acc[n]);
    }
    x0 = nx0; x1 = nx1;
  }

  // ---- epilogue: all three outputs transposed/coalesced through LDS.
  __syncthreads();  // all waves done reading Wl; region is free for reuse
  __bf16 (*Qs)[72]  = (__bf16(*)[72])Wl;            // [t_local 256][h 64 + pad8] = 36,864 B
  __bf16 (*Ks2)[72] = (__bf16(*)[72])(Wl + 18432);  // same, 36,864 B
  __bf16 (*Vl)[264] = (__bf16(*)[264])(Wl + 36864); // [h][t_local 256 + pad8] = 33,792 B

  // Q (n=0..3), K (n=4..7): C-layout row = quad*4+r, col = (n&3)*16 + l16
  #pragma unroll
  for (int n = 0; n < 4; ++n)
    #pragma unroll
    for (int r = 0; r < 4; ++r) {
      int t = wq * 16 + quad * 4 + r;
      int h = n * 16 + l16;
      Qs[t][h]  = (__bf16)acc[n][r];
      Ks2[t][h] = (__bf16)acc[n + 4][r];
    }
  // V (n=8..11): transposed [h][t]
  #pragma unroll
  for (int n = 8; n < 12; ++n) {
    int h = (n - 8) * 16 + l16;
    int t0 = wq * 16 + quad * 4;
    bf16_4 p;
    p[0] = (__bf16)acc[n][0]; p[1] = (__bf16)acc[n][1];
    p[2] = (__bf16)acc[n][2]; p[3] = (__bf16)acc[n][3];
    *(bf16_4*)&Vl[h][t0] = p;
  }
  __syncthreads();

  // coalesced copy-out. Q/K: thread covers t = tid>>2, h0 = (tid&3)*16 -> 4 lanes = one 128B row.
  {
    int t = tid >> 2, h0 = (tid & 3) * 16;
    __bf16* qdst = Q + (size_t)(rowblk + t) * NH + h0;
    __bf16* kdst = K + (size_t)(rowblk + t) * NH + h0;
    const __bf16* qsrc = &Qs[t][h0];
    const __bf16* ksrc = &Ks2[t][h0];
    ((uint4*)qdst)[0] = ((const uint4*)qsrc)[0];
    ((uint4*)qdst)[1] = ((const uint4*)qsrc)[1];
    ((uint4*)kdst)[0] = ((const uint4*)ksrc)[0];
    ((uint4*)kdst)[1] = ((const uint4*)ksrc)[1];
  }
  // V: consecutive lanes -> consecutive t: coalesced
  {
    int h = tid >> 4, seg = tid & 15;
    int bb = rowblk >> 11, t0 = (rowblk & (NT - 1)) + seg * 16;
    const __bf16* src = &Vl[h][seg * 16];
    __bf16* dst = Vt + ((size_t)(bb * NH + h)) * NT + t0;
    ((uint4*)dst)[0] = ((const uint4*)src)[0];
    ((uint4*)dst)[1] = ((const uint4*)src)[1];
  }
}

// ---- kernel 3: flash attention, fold-paired for uniform work.
// This round: T5 s_setprio(1) around the MFMA clusters (2 independent blocks/CU
// desync after pass 0 -> scheduler can favor the MFMA-phase wave).
__launch_bounds__(256)
__global__ void attn_kernel(const __bf16* __restrict__ Q, const __bf16* __restrict__ K,
                            const __bf16* __restrict__ Vt, float* __restrict__ out) {
  __shared__ __bf16 Ks[2][64][72];    // [buf][s][h]
  __shared__ __bf16 Vs[2][64][72];    // [buf][h][s]
  __shared__ __bf16 Ps[4][16][72];    // per-wave P[q][s]

  const int tid  = threadIdx.x;
  const int lane = tid & 63, wq = tid >> 6;
  const int quad = lane >> 4, l16 = lane & 15;
  const int b    = blockIdx.x >> 4;
  const int pair = blockIdx.x & 15;

  const float NEG_INF = -__builtin_inff();
  const float RTHR = 8.f;  // defer-rescale threshold (log2 domain: P <= 2^8)
  const int r = tid >> 2, seg = tid & 3;  // staging: 4 threads per 64-elem row
  const __bf16* Kg = K  + (size_t)b * NT * NH;
  const __bf16* Vg = Vt + (size_t)b * NH * NT;

  for (int pass = 0; pass < 2; ++pass) {
    const int qt = pass ? pair : (31 - pair);
    const int q0 = qt * 64;
    const int nIter = qt + 1;

    // Q B-operand fragments (scale & log2e pre-folded into Wq)
    const __bf16* qrow = Q + ((size_t)(b * NT + q0 + wq * 16 + l16)) * NH + quad * 8;
    bf16_8 qf0 = *(const bf16_8*)qrow;
    bf16_8 qf1 = *(const bf16_8*)(qrow + 32);

    f32x4 o[4];
    #pragma unroll
    for (int i = 0; i < 4; ++i) o[i] = f32x4{0.f, 0.f, 0.f, 0.f};
    float m_i = NEG_INF, l_i = 0.f;

    __syncthreads();  // previous pass's readers done before restaging buf0

    // prologue: stage tile 0 into buf 0
    {
      const uint4* sK = (const uint4*)(Kg + (size_t)r * NH + seg * 16);
      uint4 ka = sK[0], kb = sK[1];
      const uint4* sV = (const uint4*)(Vg + (size_t)r * NT + seg * 16);
      uint4 va = sV[0], vb = sV[1];
      *(uint4*)&Ks[0][r][seg * 16]     = ka;
      *(uint4*)&Ks[0][r][seg * 16 + 8] = kb;
      *(uint4*)&Vs[0][r][seg * 16]     = va;
      *(uint4*)&Vs[0][r][seg * 16 + 8] = vb;
    }

    for (int i = 0; i < nIter; ++i) {
      const int cur = i & 1;
      const bool more = (i + 1 < nIter);
      uint4 nka, nkb, nva, nvb;
      if (more) {  // issue next tile's global loads; they fly across the barrier
        const int s0n = (i + 1) * 64;
        const uint4* sK = (const uint4*)(Kg + (size_t)(s0n + r) * NH + seg * 16);
        nka = sK[0]; nkb = sK[1];
        const uint4* sV = (const uint4*)(Vg + (size_t)r * NT + s0n + seg * 16);
        nva = sV[0]; nvb = sV[1];
      }
      __syncthreads();  // buf[cur] fully staged

      // S^T tiles: A=K rows (m=s), B=Q^T (n=q). D[s=quad*4+rr][q=l16]
      f32x4 s[4];
      __builtin_amdgcn_s_setprio(1);
      #pragma unroll
      for (int st = 0; st < 4; ++st) {
        bf16_8 a0 = *(const bf16_8*)&Ks[cur][st * 16 + l16][quad * 8];
        bf16_8 a1 = *(const bf16_8*)&Ks[cur][st * 16 + l16][quad * 8 + 32];
        f32x4 accv = f32x4{0.f, 0.f, 0.f, 0.f};
        accv = mfma16(a0, qf0, accv);
        accv = mfma16(a1, qf1, accv);
        s[st] = accv;
      }
      __builtin_amdgcn_s_setprio(0);

      if (i == qt) {  // diagonal tile: causal mask
        int qg = wq * 16 + l16;
        #pragma unroll
        for (int st = 0; st < 4; ++st)
          #pragma unroll
          for (int rr = 0; rr < 4; ++rr) {
            int sg = st * 16 + quad * 4 + rr;
            if (sg > qg) s[st][rr] = NEG_INF;
          }
      }

      // online softmax (log2 domain): all 16 values in-lane share q=l16
      float mx = NEG_INF;
      #pragma unroll
      for (int st = 0; st < 4; ++st)
        #pragma unroll
        for (int rr = 0; rr < 4; ++rr) mx = fmaxf(mx, s[st][rr]);
      mx = fmaxf(mx, __shfl_xor(mx, 16));
      mx = fmaxf(mx, __shfl_xor(mx, 32));

      // defer-rescale: only pay the O-rescale when the running max actually grows
      float m_new = fmaxf(m_i, mx);
      if (__any(m_new - m_i > RTHR)) {
        float alpha = exp2f(m_i - m_new);
        f32x4 av;
        #pragma unroll
        for (int rr = 0; rr < 4; ++rr) av[rr] = __shfl(alpha, quad * 4 + rr);
        #pragma unroll
        for (int nt = 0; nt < 4; ++nt)
          #pragma unroll
          for (int rr = 0; rr < 4; ++rr) o[nt][rr] *= av[rr];
        l_i *= alpha;
        m_i = m_new;
      }

      float lsum = 0.f;
      #pragma unroll
      for (int st = 0; st < 4; ++st) {
        bf16_4 pk;
        #pragma unroll
        for (int rr = 0; rr < 4; ++rr) {
          float p = exp2f(s[st][rr] - m_i);  // bounded by 2^RTHR
          lsum += p;
          pk[rr] = (__bf16)p;
        }
        *(bf16_4*)&Ps[wq][l16][st * 16 + quad * 4] = pk;
      }
      lsum += __shfl_xor(lsum, 16);
      lsum += __shfl_xor(lsum, 32);
      l_i += lsum;

      // PV: A = P (own wave's LDS), B = V from Vs[cur][h][s]
      bf16_8 pa0 = *(const bf16_8*)&Ps[wq][l16][quad * 8];
      bf16_8 pa1 = *(const bf16_8*)&Ps[wq][l16][quad * 8 + 32];
      __builtin_amdgcn_s_setprio(1);
      #pragma unroll
      for (int nt = 0; nt < 4; ++nt) {
        bf16_8 b0 = *(const bf16_8*)&Vs[cur][nt * 16 + l16][quad * 8];
        bf16_8 b1 = *(const bf16_8*)&Vs[cur][nt * 16 + l16][quad * 8 + 32];
        o[nt] = mfma16(pa0, b0, o[nt]);
        o[nt] = mfma16(pa1, b1, o[nt]);
      }
      __builtin_amdgcn_s_setprio(0);

      if (more) {  // write next tile into the other buffer (no one reads it now)
        *(uint4*)&Ks[1 - cur][r][seg * 16]     = nka;
        *(uint4*)&Ks[1 - cur][r][seg * 16 + 8] = nkb;
        *(uint4*)&Vs[1 - cur][r][seg * 16]     = nva;
        *(uint4*)&Vs[1 - cur][r][seg * 16 + 8] = nvb;
      }
    }

    // epilogue: divide by l, store fp32
    f32x4 lv;
    #pragma unroll
    for (int rr = 0; rr < 4; ++rr) lv[rr] = 1.f / __shfl(l_i, quad * 4 + rr);
    float* op = out + ((size_t)(b * NT + q0 + wq * 16 + quad * 4)) * NH + l16;
    #pragma unroll
    for (int nt = 0; nt < 4; ++nt)
      #pragma unroll
      for (int rr = 0; rr < 4; ++rr)
        op[(size_t)rr * NH + nt * 16] = o[nt][rr] * lv[rr];
  }
}

extern "C" void kernel_launch(void* const* d_in, const int* in_sizes, int n_in,
                              void* d_out, int out_size, void* d_ws, size_t ws_size,
                              hipStream_t stream) {
  const float* x  = (const float*)d_in[0];
  const float* Wk = (const float*)d_in[1];
  const float* Wq = (const float*)d_in[2];
  const float* Wv = (const float*)d_in[3];
  float* out = (float*)d_out;

  char* ws = (char*)d_ws;
  __bf16* Wt  = (__bf16*)ws;                       // 192*384*2 = 147,456 B
  __bf16* Qb  = (__bf16*)(ws + 256 * 1024);        // each 32*2048*64*2 = 8 MiB
  __bf16* Kb  = Qb + (size_t)NB * NT * NH;
  __bf16* Vtb = Kb + (size_t)NB * NT * NH;

  pack_w_kernel<<<288, 256, 0, stream>>>(Wk, Wq, Wv, Wt);
  qkv_kernel<<<256, 1024, 0, stream>>>(x, Wt, Qb, Kb, Vtb);
  attn_kernel<<<NB * 16, 256, 0, stream>>>(Qb, Kb, Vtb, out);
}

// Round 5
// 207.344 us; speedup vs baseline: 1.0171x; 1.0171x over previous
//
#include <hip/hip_runtime.h>

typedef __bf16 bf16_8 __attribute__((ext_vector_type(8)));
typedef __bf16 bf16_4 __attribute__((ext_vector_type(4)));
typedef float  f32x4  __attribute__((ext_vector_type(4)));

#define NB 32
#define NT 2048
#define NC 384
#define NH 64

static __device__ __forceinline__ f32x4 mfma16(bf16_8 a, bf16_8 b, f32x4 c) {
  return __builtin_amdgcn_mfma_f32_16x16x32_bf16(a, b, c, 0, 0, 0);
}

// ---- kernel 1: pack weights: fp32 [C,H] x3 -> bf16 Wt[n][k], n: 0-63=Q(Wq*0.125*log2e), 64-127=K, 128-191=V
__global__ void pack_w_kernel(const float* __restrict__ Wk, const float* __restrict__ Wq,
                              const float* __restrict__ Wv, __bf16* __restrict__ Wt) {
  int idx = blockIdx.x * 256 + threadIdx.x;
  if (idx >= 192 * NC) return;
  int n = idx / NC, k = idx % NC;
  int sel = n >> 6, h = n & 63;
  const float* W = (sel == 0) ? Wq : (sel == 1 ? Wk : Wv);
  float v = W[k * NH + h];
  // fold attention scale H^-0.5 = 0.125 AND log2(e) so softmax runs on native exp2
  if (sel == 0) v *= 0.125f * 1.44269504088896340736f;
  Wt[idx] = (__bf16)v;
}

// ---- kernel 2: QKV projection with the ENTIRE Wt in LDS (147,456 B, XOR-swizzled).
// Block = 1024 threads (16 waves), 256 rows/block, grid 256 = 1 block/CU.
// All three outputs routed through LDS so every global store is a coalesced 16B.
__launch_bounds__(1024, 4)
__global__ void qkv_kernel(const float* __restrict__ x, const __bf16* __restrict__ Wt,
                           __bf16* __restrict__ Q, __bf16* __restrict__ K,
                           __bf16* __restrict__ Vt) {
  __shared__ __bf16 Wl[192 * 384];  // 147,456 B; chunk c of row r stored at c^(r&7)

  const int tid  = threadIdx.x;
  const int lane = tid & 63, wq = tid >> 6;
  const int quad = lane >> 4, l16 = lane & 15;
  const int rowblk = blockIdx.x * 256;
  const int rbase  = rowblk + wq * 16;
  const int row    = rbase + l16;  // this lane's x row

  // stage Wt -> LDS, 16-B chunks, XOR swizzle. 9216 chunks / 1024 threads = 9 each.
  #pragma unroll
  for (int i = 0; i < 9; ++i) {
    int g = tid + i * 1024;
    int r = g / 48, c = g - r * 48;
    int p = c ^ (r & 7);
    uint4 v = ((const uint4*)Wt)[g];
    *(uint4*)&Wl[(r * 48 + p) * 8] = v;
  }
  __syncthreads();

  f32x4 acc[12];
  #pragma unroll
  for (int n = 0; n < 12; ++n) acc[n] = f32x4{0.f, 0.f, 0.f, 0.f};

  const float* xrow = x + (size_t)row * NC;
  f32x4 x0 = *(const f32x4*)(xrow + quad * 8);
  f32x4 x1 = *(const f32x4*)(xrow + quad * 8 + 4);

  #pragma unroll
  for (int kc = 0; kc < 12; ++kc) {
    f32x4 nx0, nx1;
    if (kc < 11) {  // prefetch next x slab before the MFMA chain
      const float* xp = xrow + (kc + 1) * 32 + quad * 8;
      nx0 = *(const f32x4*)xp;
      nx1 = *(const f32x4*)(xp + 4);
    }
    bf16_8 a;
    a[0] = (__bf16)x0[0]; a[1] = (__bf16)x0[1]; a[2] = (__bf16)x0[2]; a[3] = (__bf16)x0[3];
    a[4] = (__bf16)x1[0]; a[5] = (__bf16)x1[1]; a[6] = (__bf16)x1[2]; a[7] = (__bf16)x1[3];
    const int pc = (kc * 4 + quad) ^ (l16 & 7);  // swizzled chunk within row
    const int cbase = l16 * 48 + pc;             // row l16 (+ n*16 rows below)
    #pragma unroll
    for (int n = 0; n < 12; ++n) {
      bf16_8 b = *(const bf16_8*)&Wl[(n * 16 * 48 + cbase) * 8];
      acc[n] = mfma16(a, b, acc[n]);
    }
    x0 = nx0; x1 = nx1;
  }

  // ---- epilogue: all three outputs transposed/coalesced through LDS.
  __syncthreads();  // all waves done reading Wl; region is free for reuse
  __bf16 (*Qs)[72]  = (__bf16(*)[72])Wl;            // [t_local 256][h 64 + pad8] = 36,864 B
  __bf16 (*Ks2)[72] = (__bf16(*)[72])(Wl + 18432);  // same, 36,864 B
  __bf16 (*Vl)[264] = (__bf16(*)[264])(Wl + 36864); // [h][t_local 256 + pad8] = 33,792 B

  // Q (n=0..3), K (n=4..7): C-layout row = quad*4+r, col = (n&3)*16 + l16
  #pragma unroll
  for (int n = 0; n < 4; ++n)
    #pragma unroll
    for (int r = 0; r < 4; ++r) {
      int t = wq * 16 + quad * 4 + r;
      int h = n * 16 + l16;
      Qs[t][h]  = (__bf16)acc[n][r];
      Ks2[t][h] = (__bf16)acc[n + 4][r];
    }
  // V (n=8..11): transposed [h][t]
  #pragma unroll
  for (int n = 8; n < 12; ++n) {
    int h = (n - 8) * 16 + l16;
    int t0 = wq * 16 + quad * 4;
    bf16_4 p;
    p[0] = (__bf16)acc[n][0]; p[1] = (__bf16)acc[n][1];
    p[2] = (__bf16)acc[n][2]; p[3] = (__bf16)acc[n][3];
    *(bf16_4*)&Vl[h][t0] = p;
  }
  __syncthreads();

  // coalesced copy-out. Q/K: thread covers t = tid>>2, h0 = (tid&3)*16 -> 4 lanes = one 128B row.
  {
    int t = tid >> 2, h0 = (tid & 3) * 16;
    __bf16* qdst = Q + (size_t)(rowblk + t) * NH + h0;
    __bf16* kdst = K + (size_t)(rowblk + t) * NH + h0;
    const __bf16* qsrc = &Qs[t][h0];
    const __bf16* ksrc = &Ks2[t][h0];
    ((uint4*)qdst)[0] = ((const uint4*)qsrc)[0];
    ((uint4*)qdst)[1] = ((const uint4*)qsrc)[1];
    ((uint4*)kdst)[0] = ((const uint4*)ksrc)[0];
    ((uint4*)kdst)[1] = ((const uint4*)ksrc)[1];
  }
  // V: consecutive lanes -> consecutive t: coalesced
  {
    int h = tid >> 4, seg = tid & 15;
    int bb = rowblk >> 11, t0 = (rowblk & (NT - 1)) + seg * 16;
    const __bf16* src = &Vl[h][seg * 16];
    __bf16* dst = Vt + ((size_t)(bb * NH + h)) * NT + t0;
    ((uint4*)dst)[0] = ((const uint4*)src)[0];
    ((uint4*)dst)[1] = ((const uint4*)src)[1];
  }
}

// ---- kernel 3: flash attention, fold-paired for uniform work.
// This round: P never touches LDS. PV contracts s in permuted order
// sperm(k) = (k&32) + ((k&7)>>2)*16 + ((k>>3)&3)*4 + (k&3), which makes the
// MFMA A-operand lane-local (each lane's S^T outputs ARE its A-slots), with V's
// s-columns staged into LDS pre-permuted to match. Removes 4 ds_write + lgkmcnt
// + 2 ds_read_b128 from every iteration's serial chain; Ps buffer deleted.
__launch_bounds__(256)
__global__ void attn_kernel(const __bf16* __restrict__ Q, const __bf16* __restrict__ K,
                            const __bf16* __restrict__ Vt, float* __restrict__ out) {
  __shared__ __bf16 Ks[2][64][72];    // [buf][s][h]
  __shared__ __bf16 Vs[2][64][72];    // [buf][h][k]  (k = s-permuted column)

  const int tid  = threadIdx.x;
  const int lane = tid & 63, wq = tid >> 6;
  const int quad = lane >> 4, l16 = lane & 15;
  const int b    = blockIdx.x >> 4;
  const int pair = blockIdx.x & 15;

  const float NEG_INF = -__builtin_inff();
  const float RTHR = 8.f;  // defer-rescale threshold (log2 domain: P <= 2^8)
  const int r = tid >> 2, seg = tid & 3;  // staging: 4 threads per 64-elem row
  const __bf16* Kg = K  + (size_t)b * NT * NH;
  const __bf16* Vg = Vt + (size_t)b * NH * NT;

  // k-chunk positions for the 4 s-chunks (4 elems each) this thread stages:
  // s-chunk c -> k4(c) = (c&8)*4 + (c&3)*8 + ((c>>2)&1)*4  [elements]
  const int c0 = seg * 4;
  const int kp0 = ((c0 & 8) << 2) + ((c0 & 3) << 3) + (((c0 >> 2) & 1) << 2);
  const int kp1 = (((c0+1) & 8) << 2) + (((c0+1) & 3) << 3) + ((((c0+1) >> 2) & 1) << 2);
  const int kp2 = (((c0+2) & 8) << 2) + (((c0+2) & 3) << 3) + ((((c0+2) >> 2) & 1) << 2);
  const int kp3 = (((c0+3) & 8) << 2) + (((c0+3) & 3) << 3) + ((((c0+3) >> 2) & 1) << 2);

  for (int pass = 0; pass < 2; ++pass) {
    const int qt = pass ? pair : (31 - pair);
    const int q0 = qt * 64;
    const int nIter = qt + 1;

    // Q B-operand fragments (scale & log2e pre-folded into Wq)
    const __bf16* qrow = Q + ((size_t)(b * NT + q0 + wq * 16 + l16)) * NH + quad * 8;
    bf16_8 qf0 = *(const bf16_8*)qrow;
    bf16_8 qf1 = *(const bf16_8*)(qrow + 32);

    f32x4 o[4];
    #pragma unroll
    for (int i = 0; i < 4; ++i) o[i] = f32x4{0.f, 0.f, 0.f, 0.f};
    float m_i = NEG_INF, l_i = 0.f;

    __syncthreads();  // previous pass's readers done before restaging buf0

    // prologue: stage tile 0 into buf 0
    {
      const uint4* sK = (const uint4*)(Kg + (size_t)r * NH + seg * 16);
      uint4 ka = sK[0], kb = sK[1];
      const uint4* sV = (const uint4*)(Vg + (size_t)r * NT + seg * 16);
      uint4 va = sV[0], vb = sV[1];
      *(uint4*)&Ks[0][r][seg * 16]     = ka;
      *(uint4*)&Ks[0][r][seg * 16 + 8] = kb;
      *(uint2*)&Vs[0][r][kp0] = make_uint2(va.x, va.y);
      *(uint2*)&Vs[0][r][kp1] = make_uint2(va.z, va.w);
      *(uint2*)&Vs[0][r][kp2] = make_uint2(vb.x, vb.y);
      *(uint2*)&Vs[0][r][kp3] = make_uint2(vb.z, vb.w);
    }

    for (int i = 0; i < nIter; ++i) {
      const int cur = i & 1;
      const bool more = (i + 1 < nIter);
      uint4 nka, nkb, nva, nvb;
      if (more) {  // issue next tile's global loads; they fly across the barrier
        const int s0n = (i + 1) * 64;
        const uint4* sK = (const uint4*)(Kg + (size_t)(s0n + r) * NH + seg * 16);
        nka = sK[0]; nkb = sK[1];
        const uint4* sV = (const uint4*)(Vg + (size_t)r * NT + s0n + seg * 16);
        nva = sV[0]; nvb = sV[1];
      }
      __syncthreads();  // buf[cur] fully staged

      // S^T tiles: A=K rows (m=s), B=Q^T (n=q). D[s=quad*4+rr][q=l16]
      f32x4 s[4];
      __builtin_amdgcn_s_setprio(1);
      #pragma unroll
      for (int st = 0; st < 4; ++st) {
        bf16_8 a0 = *(const bf16_8*)&Ks[cur][st * 16 + l16][quad * 8];
        bf16_8 a1 = *(const bf16_8*)&Ks[cur][st * 16 + l16][quad * 8 + 32];
        f32x4 accv = f32x4{0.f, 0.f, 0.f, 0.f};
        accv = mfma16(a0, qf0, accv);
        accv = mfma16(a1, qf1, accv);
        s[st] = accv;
      }
      __builtin_amdgcn_s_setprio(0);

      if (i == qt) {  // diagonal tile: causal mask
        int qg = wq * 16 + l16;
        #pragma unroll
        for (int st = 0; st < 4; ++st)
          #pragma unroll
          for (int rr = 0; rr < 4; ++rr) {
            int sg = st * 16 + quad * 4 + rr;
            if (sg > qg) s[st][rr] = NEG_INF;
          }
      }

      // online softmax (log2 domain): all 16 values in-lane share q=l16
      float mx = NEG_INF;
      #pragma unroll
      for (int st = 0; st < 4; ++st)
        #pragma unroll
        for (int rr = 0; rr < 4; ++rr) mx = fmaxf(mx, s[st][rr]);
      mx = fmaxf(mx, __shfl_xor(mx, 16));
      mx = fmaxf(mx, __shfl_xor(mx, 32));

      // defer-rescale: only pay the O-rescale when the running max actually grows
      float m_new = fmaxf(m_i, mx);
      if (__any(m_new - m_i > RTHR)) {
        float alpha = exp2f(m_i - m_new);
        f32x4 av;
        #pragma unroll
        for (int rr = 0; rr < 4; ++rr) av[rr] = __shfl(alpha, quad * 4 + rr);
        #pragma unroll
        for (int nt = 0; nt < 4; ++nt)
          #pragma unroll
          for (int rr = 0; rr < 4; ++rr) o[nt][rr] *= av[rr];
        l_i *= alpha;
        m_i = m_new;
      }

      // P stays in registers: pa0 <- st 0,1 ; pa1 <- st 2,3 (matches sperm'd V)
      float lsum = 0.f;
      bf16_8 pa0, pa1;
      #pragma unroll
      for (int st = 0; st < 4; ++st)
        #pragma unroll
        for (int rr = 0; rr < 4; ++rr) {
          float p = exp2f(s[st][rr] - m_i);  // bounded by 2^RTHR
          lsum += p;
          __bf16 pb = (__bf16)p;
          if (st < 2) pa0[st * 4 + rr] = pb;
          else        pa1[(st - 2) * 4 + rr] = pb;
        }
      lsum += __shfl_xor(lsum, 16);
      lsum += __shfl_xor(lsum, 32);
      l_i += lsum;

      // PV: A = P (in registers), B = V from Vs[cur][h][k] (s-permuted columns)
      __builtin_amdgcn_s_setprio(1);
      #pragma unroll
      for (int nt = 0; nt < 4; ++nt) {
        bf16_8 b0 = *(const bf16_8*)&Vs[cur][nt * 16 + l16][quad * 8];
        bf16_8 b1 = *(const bf16_8*)&Vs[cur][nt * 16 + l16][quad * 8 + 32];
        o[nt] = mfma16(pa0, b0, o[nt]);
        o[nt] = mfma16(pa1, b1, o[nt]);
      }
      __builtin_amdgcn_s_setprio(0);

      if (more) {  // write next tile into the other buffer (no one reads it now)
        *(uint4*)&Ks[1 - cur][r][seg * 16]     = nka;
        *(uint4*)&Ks[1 - cur][r][seg * 16 + 8] = nkb;
        *(uint2*)&Vs[1 - cur][r][kp0] = make_uint2(nva.x, nva.y);
        *(uint2*)&Vs[1 - cur][r][kp1] = make_uint2(nva.z, nva.w);
        *(uint2*)&Vs[1 - cur][r][kp2] = make_uint2(nvb.x, nvb.y);
        *(uint2*)&Vs[1 - cur][r][kp3] = make_uint2(nvb.z, nvb.w);
      }
    }

    // epilogue: divide by l, store fp32
    f32x4 lv;
    #pragma unroll
    for (int rr = 0; rr < 4; ++rr) lv[rr] = 1.f / __shfl(l_i, quad * 4 + rr);
    float* op = out + ((size_t)(b * NT + q0 + wq * 16 + quad * 4)) * NH + l16;
    #pragma unroll
    for (int nt = 0; nt < 4; ++nt)
      #pragma unroll
      for (int rr = 0; rr < 4; ++rr)
        op[(size_t)rr * NH + nt * 16] = o[nt][rr] * lv[rr];
  }
}

extern "C" void kernel_launch(void* const* d_in, const int* in_sizes, int n_in,
                              void* d_out, int out_size, void* d_ws, size_t ws_size,
                              hipStream_t stream) {
  const float* x  = (const float*)d_in[0];
  const float* Wk = (const float*)d_in[1];
  const float* Wq = (const float*)d_in[2];
  const float* Wv = (const float*)d_in[3];
  float* out = (float*)d_out;

  char* ws = (char*)d_ws;
  __bf16* Wt  = (__bf16*)ws;                       // 192*384*2 = 147,456 B
  __bf16* Qb  = (__bf16*)(ws + 256 * 1024);        // each 32*2048*64*2 = 8 MiB
  __bf16* Kb  = Qb + (size_t)NB * NT * NH;
  __bf16* Vtb = Kb + (size_t)NB * NT * NH;

  pack_w_kernel<<<288, 256, 0, stream>>>(Wk, Wq, Wv, Wt);
  qkv_kernel<<<256, 1024, 0, stream>>>(x, Wt, Qb, Kb, Vtb);
  attn_kernel<<<NB * 16, 256, 0, stream>>>(Qb, Kb, Vtb, out);
}